// Round 2
// baseline (59.873 us; speedup 1.0000x reference)
//
#include <hip/hip_runtime.h>
#include <hip/hip_bf16.h>

typedef __bf16 bf16x4 __attribute__((ext_vector_type(4)));
typedef __bf16 bf16x8 __attribute__((ext_vector_type(8)));
typedef float f32x4 __attribute__((ext_vector_type(4)));

#define B_    8
#define NTOK  4096
#define CIN   512
#define COUT  512
#define SDIM  512
#define EPSF  1e-8f

// ---------------------------------------------------------------------------
// K1: m[b][i] = style[b,:] . mod_w[i,:] + mod_b[i] + 1    (one wave per output)
// ---------------------------------------------------------------------------
__global__ __launch_bounds__(256) void k_stylefc(
    const float* __restrict__ style, const float* __restrict__ mod_w,
    const float* __restrict__ mod_b, float* __restrict__ m_out) {
  int gw   = (blockIdx.x * 256 + threadIdx.x) >> 6;  // 0..4095
  int lane = threadIdx.x & 63;
  int b = gw >> 9;
  int i = gw & 511;
  const float* srow = style + (size_t)b * SDIM;
  const float* wrow = mod_w + (size_t)i * SDIM;
  float acc = 0.f;
#pragma unroll
  for (int k = 0; k < SDIM; k += 64) acc += srow[k + lane] * wrow[k + lane];
#pragma unroll
  for (int off = 32; off; off >>= 1) acc += __shfl_xor(acc, off, 64);
  if (lane == 0) m_out[b * CIN + i] = acc + mod_b[i] + 1.0f;
}

// ---------------------------------------------------------------------------
// K2: per output-channel o:
//   demod[b][o] = rsqrt( sum_i (weight[i][o]*m[b][i])^2 + eps )  for all 8 b
//   wT[o][i]    = bf16(weight[i][o])   (transposed for GEMM B staging)
// ---------------------------------------------------------------------------
__global__ __launch_bounds__(256) void k_wprep(
    const float* __restrict__ weight, const float* __restrict__ m_buf,
    __bf16* __restrict__ wT, float* __restrict__ demod) {
  int o = blockIdx.x;
  int tid = threadIdx.x;
  int wid = tid >> 6, lane = tid & 63;
  float acc[B_] = {0.f, 0.f, 0.f, 0.f, 0.f, 0.f, 0.f, 0.f};
#pragma unroll
  for (int rep = 0; rep < 2; ++rep) {
    int i = tid + rep * 256;
    float w = weight[(size_t)i * COUT + o];
    wT[(size_t)o * CIN + i] = (__bf16)w;
#pragma unroll
    for (int b = 0; b < B_; ++b) {
      float wm = w * m_buf[b * CIN + i];
      acc[b] += wm * wm;
    }
  }
  __shared__ float red[4][B_];
#pragma unroll
  for (int b = 0; b < B_; ++b) {
    float v = acc[b];
#pragma unroll
    for (int off = 32; off; off >>= 1) v += __shfl_xor(v, off, 64);
    if (lane == 0) red[wid][b] = v;
  }
  __syncthreads();
  if (tid < B_) {
    float s = red[0][tid] + red[1][tid] + red[2][tid] + red[3][tid];
    demod[tid * COUT + o] = rsqrtf(s + EPSF);
  }
}

// ---------------------------------------------------------------------------
// async global->LDS, 16B per lane (dest = wave-uniform base + lane*16)
// ---------------------------------------------------------------------------
__device__ __forceinline__ void async_copy16(void* lds_dst, const void* gsrc) {
  __builtin_amdgcn_global_load_lds(
      (const __attribute__((address_space(1))) unsigned int*)gsrc,
      (__attribute__((address_space(3))) unsigned int*)lds_dst, 16, 0, 0);
}

// ---------------------------------------------------------------------------
// K3: out[b, t, o] = demod[b][o] * sum_i (x[b,t,i]*m[b][i]) * wT[o][i]
// 128x128 tile, BK=32, 256 thr (4 waves 2x2), mfma_f32_16x16x32_bf16.
// T3 minimal 2-phase pipeline: LDS double-buffered; next-tile loads issued
// BEFORE current-tile MFMA; one barrier per K-step.
// A: reg-staged (f32 load -> *m -> bf16 cvt), XOR-swizzled LDS (conflict-free).
// B: global_load_lds width=16 into linear LDS (bf16 already; no VALU cost).
// ---------------------------------------------------------------------------
__global__ __launch_bounds__(256, 4) void k_gemm(
    const float* __restrict__ x, const __bf16* __restrict__ wT,
    const float* __restrict__ m_buf, const float* __restrict__ demod,
    float* __restrict__ out) {
  // decode: 1024 blocks = 8 xcd * 32 panels * 4 nb (4 nb of one panel -> same XCD)
  int bid  = blockIdx.x;
  int xcd  = bid & 7;
  int slot = bid >> 3;                 // 0..127
  int panel = xcd * 32 + (slot >> 2);  // 0..255
  int nb   = slot & 3;
  int b    = panel >> 5;               // 0..7
  int mb   = panel & 31;               // 0..31

  // LDS 32 KiB: A0 [0,8K)  A1 [8K,16K)  B0 [16K,24K)  B1 [24K,32K)
  __shared__ uint4 lds_u4[2048];
  char* lds = (char*)lds_u4;
  char* Ab0 = lds;
  char* Ab1 = lds + 8192;
  char* Bb0 = lds + 16384;
  char* Bb1 = lds + 24576;

  int tid  = threadIdx.x;
  int wid  = tid >> 6, lane = tid & 63;
  int wr   = wid >> 1, wc = wid & 1;

  f32x4 acc[4][4] = {};

  const float*  xbase = x + ((size_t)b * NTOK + (size_t)mb * 128) * CIN;
  const float*  mrow  = m_buf + b * CIN;
  const __bf16* wTb   = wT + (size_t)(nb * 128) * CIN;

  int arow = tid >> 3, aseg = tid & 7;   // A: 32 rows/pass, 4-f32 segment

  float4 xa[4];
  float4 mv;

  auto loadA = [&](int k0) {
    mv = *(const float4*)(mrow + k0 + aseg * 4);
#pragma unroll
    for (int p = 0; p < 4; ++p)
      xa[p] = *(const float4*)(xbase + (size_t)(arow + p * 32) * CIN + k0 + aseg * 4);
  };
  auto writeA = [&](char* Ab) {
#pragma unroll
    for (int p = 0; p < 4; ++p) {
      int r = arow + p * 32;
      bf16x4 hv;
      hv[0] = (__bf16)(xa[p].x * mv.x);
      hv[1] = (__bf16)(xa[p].y * mv.y);
      hv[2] = (__bf16)(xa[p].z * mv.z);
      hv[3] = (__bf16)(xa[p].w * mv.w);
      int sw = (aseg >> 1) ^ ((r >> 1) & 3);
      *(bf16x4*)(Ab + r * 64 + sw * 16 + (aseg & 1) * 8) = hv;
    }
  };
  auto issueB = [&](int k0, char* Bb) {
    // per wave: 2 gload_lds, 16 rows (o) each; linear LDS row*64 + chunk*16
#pragma unroll
    for (int inst = 0; inst < 2; ++inst) {
      int row = wid * 32 + inst * 16 + (lane >> 2);
      const char* g = (const char*)(wTb + (size_t)row * CIN + k0) + (lane & 3) * 16;
      async_copy16(Bb + wid * 2048 + inst * 1024, g);
    }
  };
  auto mmaStep = [&](const char* Ab, const char* Bb) {
    bf16x8 af[4], bfr[4];
#pragma unroll
    for (int mm = 0; mm < 4; ++mm) {
      int r = wr * 64 + mm * 16 + (lane & 15);
      int sw = (lane >> 4) ^ ((r >> 1) & 3);
      af[mm] = *(const bf16x8*)(Ab + r * 64 + sw * 16);
    }
#pragma unroll
    for (int nn = 0; nn < 4; ++nn) {
      int r = wc * 64 + nn * 16 + (lane & 15);
      bfr[nn] = *(const bf16x8*)(Bb + r * 64 + (lane >> 4) * 16);
    }
#pragma unroll
    for (int mm = 0; mm < 4; ++mm)
#pragma unroll
      for (int nn = 0; nn < 4; ++nn)
        acc[mm][nn] = __builtin_amdgcn_mfma_f32_16x16x32_bf16(
            af[mm], bfr[nn], acc[mm][nn], 0, 0, 0);
  };

  // prologue: stage K-step 0 into buf0
  loadA(0);
  issueB(0, Bb0);
  writeA(Ab0);
  __syncthreads();  // drains vmcnt (incl. gload_lds) + lgkm

  // steady state: read buf[ks&1], prefetch into buf[(ks+1)&1], 1 barrier/step
#pragma unroll
  for (int ks = 0; ks < 15; ++ks) {
    const bool cur0 = ((ks & 1) == 0);
    char* Ac = cur0 ? Ab0 : Ab1;
    char* Bc = cur0 ? Bb0 : Bb1;
    char* An = cur0 ? Ab1 : Ab0;
    char* Bn = cur0 ? Bb1 : Bb0;
    int k0n = (ks + 1) * 32;
    issueB(k0n, Bn);       // async, lands any time before next barrier
    loadA(k0n);            // global->reg, latency hidden under MFMA
    mmaStep(Ac, Bc);
    writeA(An);            // waits xa via auto s_waitcnt, writes other buffer
    __syncthreads();
  }
  mmaStep(Ab1, Bb1);       // K-step 15 (15&1 == 1)

  // ---- epilogue: scale by demod[b][col], write f32 ----
  float* obase = out + ((size_t)b * NTOK + (size_t)mb * 128) * COUT + nb * 128;
  const float* drow = demod + b * COUT + nb * 128;
#pragma unroll
  for (int nn = 0; nn < 4; ++nn) {
    int col = wc * 64 + nn * 16 + (lane & 15);
    float d = drow[col];
#pragma unroll
    for (int mm = 0; mm < 4; ++mm) {
      int r0 = wr * 64 + mm * 16 + (lane >> 4) * 4;
#pragma unroll
      for (int j = 0; j < 4; ++j)
        obase[(size_t)(r0 + j) * COUT + col] = acc[mm][nn][j] * d;
    }
  }
}

// ---------------------------------------------------------------------------
extern "C" void kernel_launch(void* const* d_in, const int* in_sizes, int n_in,
                              void* d_out, int out_size, void* d_ws, size_t ws_size,
                              hipStream_t stream) {
  const float* x      = (const float*)d_in[0];  // (8,4096,512)
  const float* style  = (const float*)d_in[1];  // (8,512)
  const float* weight = (const float*)d_in[2];  // (1,512,512)
  const float* mod_w  = (const float*)d_in[3];  // (512,512)
  const float* mod_b  = (const float*)d_in[4];  // (512,)
  float* out = (float*)d_out;

  // ws layout: m[8*512] f32 | demod[8*512] f32 | wT[512*512] bf16
  float*  m_buf = (float*)d_ws;
  float*  demod = m_buf + B_ * CIN;
  __bf16* wT    = (__bf16*)((char*)d_ws + 2 * B_ * CIN * sizeof(float));

  k_stylefc<<<dim3((B_ * CIN) / 4), dim3(256), 0, stream>>>(style, mod_w, mod_b, m_buf);
  k_wprep<<<dim3(COUT), dim3(256), 0, stream>>>(weight, m_buf, wT, demod);
  k_gemm<<<dim3(8 * 32 * 4), dim3(256), 0, stream>>>(x, wT, m_buf, demod, out);
}

// Round 3
// 54.394 us; speedup vs baseline: 1.1007x; 1.1007x over previous
//
#include <hip/hip_runtime.h>
#include <hip/hip_bf16.h>

typedef __bf16 bf16x4 __attribute__((ext_vector_type(4)));
typedef __bf16 bf16x8 __attribute__((ext_vector_type(8)));
typedef float f32x4 __attribute__((ext_vector_type(4)));

#define B_    8
#define NTOK  4096
#define CIN   512
#define COUT  512
#define SDIM  512
#define EPSF  1e-8f

// ---------------------------------------------------------------------------
// K1: m[b][i] = style[b,:] . mod_w[i,:] + mod_b[i] + 1    (one wave per output)
// ---------------------------------------------------------------------------
__global__ __launch_bounds__(256) void k_stylefc(
    const float* __restrict__ style, const float* __restrict__ mod_w,
    const float* __restrict__ mod_b, float* __restrict__ m_out) {
  int gw   = (blockIdx.x * 256 + threadIdx.x) >> 6;  // 0..4095
  int lane = threadIdx.x & 63;
  int b = gw >> 9;
  int i = gw & 511;
  const float* srow = style + (size_t)b * SDIM;
  const float* wrow = mod_w + (size_t)i * SDIM;
  float acc = 0.f;
#pragma unroll
  for (int k = 0; k < SDIM; k += 64) acc += srow[k + lane] * wrow[k + lane];
#pragma unroll
  for (int off = 32; off; off >>= 1) acc += __shfl_xor(acc, off, 64);
  if (lane == 0) m_out[b * CIN + i] = acc + mod_b[i] + 1.0f;
}

// ---------------------------------------------------------------------------
// K2: demod[b][o] = rsqrt( sum_i (weight[i][o]*m[b][i])^2 + eps )
// one block (256 thr) per o
// ---------------------------------------------------------------------------
__global__ __launch_bounds__(256) void k_demod(
    const float* __restrict__ weight, const float* __restrict__ m_buf,
    float* __restrict__ demod) {
  int o = blockIdx.x;
  int tid = threadIdx.x;
  int wid = tid >> 6, lane = tid & 63;
  float acc[B_] = {0.f, 0.f, 0.f, 0.f, 0.f, 0.f, 0.f, 0.f};
#pragma unroll
  for (int rep = 0; rep < 2; ++rep) {
    int i = tid + rep * 256;
    float w = weight[(size_t)i * COUT + o];
#pragma unroll
    for (int b = 0; b < B_; ++b) {
      float wm = w * m_buf[b * CIN + i];
      acc[b] += wm * wm;
    }
  }
  __shared__ float red[4][B_];
#pragma unroll
  for (int b = 0; b < B_; ++b) {
    float v = acc[b];
#pragma unroll
    for (int off = 32; off; off >>= 1) v += __shfl_xor(v, off, 64);
    if (lane == 0) red[wid][b] = v;
  }
  __syncthreads();
  if (tid < B_) {
    float s = red[0][tid] + red[1][tid] + red[2][tid] + red[3][tid];
    demod[tid * COUT + o] = rsqrtf(s + EPSF);
  }
}

// ---------------------------------------------------------------------------
// K2b: build B image = exact byte image of the GEMM's swizzled LDS B-tile.
// LDS B-tile layout (per nb,kt): row o_local in [0,128), k in [0,64) bf16:
//   elem_idx(row,k) = row*64 + ((k>>3) ^ (row&7))*8 + (k&7)
// Image element p2 (0..8191) inverts to:
//   row = p2>>6; slotw = (p2>>3)&7; k = ((slotw ^ (row&7))<<3) | (p2&7)
// value = bf16( weight[(kt*64+k)*COUT + nb*128+row] )
// grid: 32 blocks = (nb 0..3) x (kt 0..7), 256 thr, 32 elems/thr
// ---------------------------------------------------------------------------
__global__ __launch_bounds__(256) void k_bimg(
    const float* __restrict__ weight, __bf16* __restrict__ img) {
  int nb = blockIdx.x >> 3;
  int kt = blockIdx.x & 7;
  int tid = threadIdx.x;
  __bf16* base = img + (size_t)(nb * 8 + kt) * 8192;
#pragma unroll
  for (int e8 = 0; e8 < 32; ++e8) {
    int p2 = e8 * 256 + tid;
    int row = p2 >> 6;
    int slotw = (p2 >> 3) & 7;
    int k = ((slotw ^ (row & 7)) << 3) | (p2 & 7);
    int i = kt * 64 + k;
    int o = nb * 128 + row;
    base[p2] = (__bf16)weight[(size_t)i * COUT + o];
  }
}

// ---------------------------------------------------------------------------
// async global->LDS: dest = wave-uniform LDS base (+lane*16 by HW), src per-lane
// ---------------------------------------------------------------------------
__device__ __forceinline__ void async_copy16(void* lds_dst, const void* gsrc) {
  __builtin_amdgcn_global_load_lds(
      (const __attribute__((address_space(1))) unsigned int*)gsrc,
      (__attribute__((address_space(3))) unsigned int*)lds_dst, 16, 0, 0);
}

// ---------------------------------------------------------------------------
// K3: out[b, t, o] = demod[b][o] * sum_i (x[b,t,i]*m[b][i]) * wT[o][i]
// 128x128 tile, BK=64, 256 thr (4 waves 2x2), mfma_f32_16x16x32_bf16.
// 2-phase pipeline, dbuf 64 KiB LDS, 1 barrier per K-tile (8 tiles).
// A: reg-staged (f32 -> *m -> bf16), XOR-swizzled (slot ^ (row&7)).
// B: global_load_lds from PRE-SWIZZLED image (linear copy, 0 conflicts).
// ---------------------------------------------------------------------------
__global__ __launch_bounds__(256) void k_gemm(
    const float* __restrict__ x, const __bf16* __restrict__ bimg,
    const float* __restrict__ m_buf, const float* __restrict__ demod,
    float* __restrict__ out) {
  // 1024 blocks = 8 xcd * 32 panels * 4 nb (4 nb of one x-panel -> same XCD)
  int bid  = blockIdx.x;
  int xcd  = bid & 7;
  int slot = bid >> 3;                 // 0..127
  int panel = xcd * 32 + (slot >> 2);  // 0..255
  int nb   = slot & 3;
  int b    = panel >> 5;               // 0..7
  int mb   = panel & 31;               // 0..31

  // LDS 64 KiB: A0 A1 B0 B1, 16 KiB each (tile = 128 rows x 64 k bf16, row=128B)
  __shared__ uint4 lds_u4[4096];
  char* lds = (char*)lds_u4;
  char* Ab0 = lds;
  char* Ab1 = lds + 16384;
  char* Bb0 = lds + 32768;
  char* Bb1 = lds + 49152;

  int tid  = threadIdx.x;
  int wid  = tid >> 6, lane = tid & 63;
  int wr   = wid >> 1, wc = wid & 1;

  f32x4 acc[4][4] = {};

  const float*  xbase = x + ((size_t)b * NTOK + (size_t)mb * 128) * CIN;
  const float*  mrow  = m_buf + b * CIN;
  const char*   bsrc  = (const char*)(bimg + (size_t)nb * 8 * 8192);

  // A staging map: 32 rows x 8 k-segments (8 bf16 = 16B slot), 4 passes
  int arow = tid >> 3, aseg8 = tid & 7;

  float4 xa[4][2];
  float4 mva, mvb;

  auto loadA = [&](int k0) {
    const float* mp = mrow + k0 + aseg8 * 8;
    mva = *(const float4*)mp;
    mvb = *(const float4*)(mp + 4);
#pragma unroll
    for (int p = 0; p < 4; ++p) {
      const float* px = xbase + (size_t)(arow + p * 32) * CIN + k0 + aseg8 * 8;
      xa[p][0] = *(const float4*)px;
      xa[p][1] = *(const float4*)(px + 4);
    }
  };
  auto writeA = [&](char* Ab) {
#pragma unroll
    for (int p = 0; p < 4; ++p) {
      int r = arow + p * 32;
      bf16x8 hv;
      hv[0] = (__bf16)(xa[p][0].x * mva.x);
      hv[1] = (__bf16)(xa[p][0].y * mva.y);
      hv[2] = (__bf16)(xa[p][0].z * mva.z);
      hv[3] = (__bf16)(xa[p][0].w * mva.w);
      hv[4] = (__bf16)(xa[p][1].x * mvb.x);
      hv[5] = (__bf16)(xa[p][1].y * mvb.y);
      hv[6] = (__bf16)(xa[p][1].z * mvb.z);
      hv[7] = (__bf16)(xa[p][1].w * mvb.w);
      *(bf16x8*)(Ab + r * 128 + ((aseg8 ^ (r & 7)) << 4)) = hv;
    }
  };
  auto issueB = [&](int kt, char* Bb) {
    const char* src = bsrc + (size_t)kt * 16384;
#pragma unroll
    for (int q = 0; q < 4; ++q) {
      int off = (wid * 4 + q) * 1024;
      async_copy16(Bb + off, src + off + lane * 16);
    }
  };
  auto mmaStep = [&](const char* Ab, const char* Bb) {
    bf16x8 af[4][2], bfr[4][2];
#pragma unroll
    for (int mm = 0; mm < 4; ++mm) {
      int r = wr * 64 + mm * 16 + (lane & 15);
#pragma unroll
      for (int kh = 0; kh < 2; ++kh) {
        int sl = kh * 4 + (lane >> 4);
        af[mm][kh] = *(const bf16x8*)(Ab + r * 128 + ((sl ^ (r & 7)) << 4));
      }
    }
#pragma unroll
    for (int nn = 0; nn < 4; ++nn) {
      int r = wc * 64 + nn * 16 + (lane & 15);
#pragma unroll
      for (int kh = 0; kh < 2; ++kh) {
        int sl = kh * 4 + (lane >> 4);
        bfr[nn][kh] = *(const bf16x8*)(Bb + r * 128 + ((sl ^ (r & 7)) << 4));
      }
    }
#pragma unroll
    for (int kh = 0; kh < 2; ++kh)
#pragma unroll
      for (int mm = 0; mm < 4; ++mm)
#pragma unroll
        for (int nn = 0; nn < 4; ++nn)
          acc[mm][nn] = __builtin_amdgcn_mfma_f32_16x16x32_bf16(
              af[mm][kh], bfr[nn][kh], acc[mm][nn], 0, 0, 0);
  };

  // prologue: K-tile 0 into buf0
  loadA(0);
  issueB(0, Bb0);
  writeA(Ab0);
  __syncthreads();

  // steady state: 1 barrier per K-tile
#pragma unroll
  for (int kt = 0; kt < 7; ++kt) {
    const bool cur0 = ((kt & 1) == 0);
    char* Ac = cur0 ? Ab0 : Ab1;
    char* Bc = cur0 ? Bb0 : Bb1;
    char* An = cur0 ? Ab1 : Ab0;
    char* Bn = cur0 ? Bb1 : Bb0;
    loadA((kt + 1) * 64);   // global->reg first (counted vmcnt won't drain B)
    issueB(kt + 1, Bn);     // async direct-to-LDS
    mmaStep(Ac, Bc);        // hide latency under MFMA
    writeA(An);
    __syncthreads();
  }
  mmaStep(Ab1, Bb1);        // K-tile 7

  // ---- epilogue: scale by demod[b][col], write f32 ----
  float* obase = out + ((size_t)b * NTOK + (size_t)mb * 128) * COUT + nb * 128;
  const float* drow = demod + b * COUT + nb * 128;
#pragma unroll
  for (int nn = 0; nn < 4; ++nn) {
    int col = wc * 64 + nn * 16 + (lane & 15);
    float d = drow[col];
#pragma unroll
    for (int mm = 0; mm < 4; ++mm) {
      int r0 = wr * 64 + mm * 16 + (lane >> 4) * 4;
#pragma unroll
      for (int j = 0; j < 4; ++j)
        obase[(size_t)(r0 + j) * COUT + col] = acc[mm][nn][j] * d;
    }
  }
}

// ---------------------------------------------------------------------------
extern "C" void kernel_launch(void* const* d_in, const int* in_sizes, int n_in,
                              void* d_out, int out_size, void* d_ws, size_t ws_size,
                              hipStream_t stream) {
  const float* x      = (const float*)d_in[0];  // (8,4096,512)
  const float* style  = (const float*)d_in[1];  // (8,512)
  const float* weight = (const float*)d_in[2];  // (1,512,512)
  const float* mod_w  = (const float*)d_in[3];  // (512,512)
  const float* mod_b  = (const float*)d_in[4];  // (512,)
  float* out = (float*)d_out;

  // ws: m[8*512] f32 | demod[8*512] f32 | bimg[4][8][8192] bf16  (544 KiB)
  float*  m_buf = (float*)d_ws;
  float*  demod = m_buf + B_ * CIN;
  __bf16* bimg  = (__bf16*)((char*)d_ws + 2 * B_ * CIN * sizeof(float));

  k_stylefc<<<dim3((B_ * CIN) / 4), dim3(256), 0, stream>>>(style, mod_w, mod_b, m_buf);
  k_demod<<<dim3(COUT), dim3(256), 0, stream>>>(weight, m_buf, demod);
  k_bimg<<<dim3(32), dim3(256), 0, stream>>>(weight, bimg);
  k_gemm<<<dim3(8 * 32 * 4), dim3(256), 0, stream>>>(x, bimg, m_buf, demod, out);
}